// Round 1
// baseline (643.138 us; speedup 1.0000x reference)
//
#include <hip/hip_runtime.h>
#include <hip/hip_bf16.h>

#define GLOBAL_AS __attribute__((address_space(1)))
#define LDS_AS    __attribute__((address_space(3)))

typedef __bf16 bf16x8 __attribute__((ext_vector_type(8)));
typedef float  f32x4  __attribute__((ext_vector_type(4)));
typedef unsigned short u16x8 __attribute__((ext_vector_type(8)));
typedef LDS_AS float ldsf_t;

#define BATCH  8192
#define KDIM   1024
#define NDIM   4096
#define NHALF  2048
#define KTILES 32   // KDIM / 32

// ---------------- fp32 -> bf16 hi/lo split helpers ----------------
__device__ __forceinline__ unsigned short bf16_rne(float f) {
  unsigned int u = __float_as_uint(f);
  u += 0x7fffu + ((u >> 16) & 1u);
  return (unsigned short)(u >> 16);
}
__device__ __forceinline__ float bf16_f32(unsigned short h) {
  return __uint_as_float(((unsigned int)h) << 16);
}

// Convert fp32 [rows][1024] into [rows][KTILES][64] bf16 where per k-tile the
// first 32 are hi parts of k=32t..32t+31, next 32 are lo parts. This makes one
// LDS row (128B) exactly one contiguous 128B span of the source -> enables
// global_load_lds with full (row&7)<<4 XOR swizzle (rule #21: swizzle source).
__global__ __launch_bounds__(256) void cvt_split(const float* __restrict__ src,
                                                 unsigned short* __restrict__ dst,
                                                 int rows) {
  int i = blockIdx.x * 256 + threadIdx.x;   // chunk id: 8 k's per chunk
  if (i >= rows * 128) return;
  int m = i >> 7, c = i & 127;
  const float4* s4 = (const float4*)(src + ((size_t)m * KDIM + c * 8));
  float4 x0 = s4[0], x1 = s4[1];
  float xs[8] = {x0.x, x0.y, x0.z, x0.w, x1.x, x1.y, x1.z, x1.w};
  u16x8 hv, lv;
#pragma unroll
  for (int j = 0; j < 8; ++j) {
    unsigned short h = bf16_rne(xs[j]);
    hv[j] = h;
    lv[j] = bf16_rne(xs[j] - bf16_f32(h));
  }
  size_t base = ((size_t)m * KTILES + (c >> 2)) * 64 + (size_t)(c & 3) * 8;
  *(u16x8*)(dst + base) = hv;        // hi chunk
  *(u16x8*)(dst + base + 32) = lv;   // lo chunk
}

// ---------------- tables: rotation cos/sin + Householder factors ----------------
// T layout (floats): [0)=T1c[2048] [2048)=T1s [4096)=T2c*(1/2048) [6144)=T2s*(1/2048)
//                    [8192)=T3c [10240)=T3s [12288]=fac1 [12289]=fac2
__global__ __launch_bounds__(256) void tables_kernel(
    const float* __restrict__ d1, const float* __restrict__ r1re, const float* __restrict__ r1im,
    const float* __restrict__ d2, const float* __restrict__ r2re, const float* __restrict__ r2im,
    const float* __restrict__ d3, float* __restrict__ T) {
  __shared__ float red[8];
  int tid = threadIdx.x;
  const float invN = 1.0f / 2048.0f;   // fold ifft 1/N into d2 rotation (linear ops commute)
  for (int j = tid; j < NHALF; j += 256) {
    float s, c;
    sincosf(d1[j], &s, &c); T[j] = c;            T[2048 + j] = s;
    sincosf(d2[j], &s, &c); T[4096 + j] = c * invN; T[6144 + j] = s * invN;
    sincosf(d3[j], &s, &c); T[8192 + j] = c;     T[10240 + j] = s;
  }
  float n1 = 0.f, n2 = 0.f;
  for (int j = tid; j < NHALF; j += 256) {
    n1 += r1re[j] * r1re[j] + r1im[j] * r1im[j];
    n2 += r2re[j] * r2re[j] + r2im[j] * r2im[j];
  }
#pragma unroll
  for (int off = 32; off; off >>= 1) {
    n1 += __shfl_down(n1, off);
    n2 += __shfl_down(n2, off);
  }
  if ((tid & 63) == 0) { red[(tid >> 6) * 2] = n1; red[(tid >> 6) * 2 + 1] = n2; }
  __syncthreads();
  if (tid == 0) {
    T[12288] = 2.0f / (red[0] + red[2] + red[4] + red[6]);
    T[12289] = 2.0f / (red[1] + red[3] + red[5] + red[7]);
  }
}

// ---------------- split-bf16 x3 MFMA GEMM: C[8192][4096] = A[8192][1024] . W[4096][1024]^T ----------------
// 128x128 tile, k-tile 32 (stored as 64 bf16: hi|lo), 4 waves in 2x2, 64x64 per wave.
__global__ __launch_bounds__(256) void gemm_split(const unsigned short* __restrict__ Acvt,
                                                  const unsigned short* __restrict__ Wcvt,
                                                  float* __restrict__ C) {
  __shared__ __attribute__((aligned(16))) unsigned short sA[128 * 64];
  __shared__ __attribute__((aligned(16))) unsigned short sW[128 * 64];

  int bid = blockIdx.x;
  int swz = (bid & 7) * 256 + (bid >> 3);   // 2048 blocks, bijective XCD swizzle
  int bm = swz >> 5;                         // 64 M-tiles
  int bn = swz & 31;                         // 32 N-tiles

  int tid = threadIdx.x;
  int w = tid >> 6, l = tid & 63;
  int wr = w >> 1, wc = w & 1;               // wave 2x2 grid
  int g = l >> 4;                            // k-chunk group (8 bf16 each)

  f32x4 acc[4][4] = {};

#pragma unroll 1
  for (int kt = 0; kt < KTILES; ++kt) {
    __syncthreads();   // previous tile's ds_reads complete before overwrite
    // stage: each wave covers 4 groups of 8 rows per matrix; lane l -> row l>>3, chunk l&7
    // LDS is linear; XOR swizzle applied on SOURCE chunk and on READ chunk (same involution)
#pragma unroll
    for (int i = 0; i < 4; ++i) {
      int rgrp = (w * 4 + i) * 8;
      int row = rgrp + (l >> 3);
      int chunk = (l & 7) ^ (l >> 3);        // (row&7) == l>>3 within 8-row group
      const unsigned short* srcA = Acvt + (((size_t)(bm * 128 + row)) * KTILES + kt) * 64 + chunk * 8;
      const unsigned short* srcW = Wcvt + (((size_t)(bn * 128 + row)) * KTILES + kt) * 64 + chunk * 8;
      __builtin_amdgcn_global_load_lds((GLOBAL_AS const void*)srcA, (LDS_AS void*)(sA + rgrp * 64), 16, 0, 0);
      __builtin_amdgcn_global_load_lds((GLOBAL_AS const void*)srcW, (LDS_AS void*)(sW + rgrp * 64), 16, 0, 0);
    }
    __syncthreads();   // compiler emits vmcnt(0) drain here (m97 structure)

    bf16x8 a_hi[4], a_lo[4], b_hi[4], b_lo[4];
#pragma unroll
    for (int mi = 0; mi < 4; ++mi) {
      int row = wr * 64 + mi * 16 + (l & 15);
      int ph = g ^ (row & 7);
      a_hi[mi] = *(const bf16x8*)&sA[row * 64 + ph * 8];
      a_lo[mi] = *(const bf16x8*)&sA[row * 64 + (ph ^ 4) * 8];
    }
#pragma unroll
    for (int ni = 0; ni < 4; ++ni) {
      int row = wc * 64 + ni * 16 + (l & 15);
      int ph = g ^ (row & 7);
      b_hi[ni] = *(const bf16x8*)&sW[row * 64 + ph * 8];
      b_lo[ni] = *(const bf16x8*)&sW[row * 64 + (ph ^ 4) * 8];
    }
#pragma unroll
    for (int mi = 0; mi < 4; ++mi)
#pragma unroll
      for (int ni = 0; ni < 4; ++ni) {
        acc[mi][ni] = __builtin_amdgcn_mfma_f32_16x16x32_bf16(a_hi[mi], b_hi[ni], acc[mi][ni], 0, 0, 0);
        acc[mi][ni] = __builtin_amdgcn_mfma_f32_16x16x32_bf16(a_hi[mi], b_lo[ni], acc[mi][ni], 0, 0, 0);
        acc[mi][ni] = __builtin_amdgcn_mfma_f32_16x16x32_bf16(a_lo[mi], b_hi[ni], acc[mi][ni], 0, 0, 0);
      }
  }

  // epilogue: C/D layout col = l&15, row = (l>>4)*4 + i  [m89/m91 verified]
  int r0 = bm * 128 + wr * 64 + g * 4;
  int c0 = bn * 128 + wc * 64 + (l & 15);
#pragma unroll
  for (int mi = 0; mi < 4; ++mi)
#pragma unroll
    for (int ni = 0; ni < 4; ++ni)
#pragma unroll
      for (int i = 0; i < 4; ++i)
        C[(size_t)(r0 + mi * 16 + i) * NDIM + (c0 + ni * 16)] = acc[mi][ni][i];
}

// ---------------- fused complex pipeline, one block per batch row ----------------
// Stockham radix-2 DIF, ping-pong in LDS. Reads src[t], src[t+1024] (coalesced),
// writes 2-way max (free per m136). Twiddle table Wt[k] = exp(-2*pi*i*k/2048).
__device__ __forceinline__ void fft_stages(ldsf_t*& sr, ldsf_t*& si, ldsf_t*& dr, ldsf_t*& di,
                                           const ldsf_t* Wc, const ldsf_t* Ws, int tid, float sgn) {
  int s = 1;
#pragma unroll 1
  for (int stage = 0; stage < 11; ++stage) {
    int smask = s - 1;
#pragma unroll
    for (int tt = 0; tt < 4; ++tt) {
      int t = tid + tt * 256;
      int q = t & smask;
      int k = t - q;                 // p*s == twiddle table index
      float ar = sr[t], ai = si[t];
      float br = sr[t + 1024], bi = si[t + 1024];
      float wr = Wc[k], wi = sgn * Ws[k];
      float er = ar + br, ei = ai + bi;
      float fr = ar - br, fi = ai - bi;
      int j0 = t + k;                // 2*p*s + q
      dr[j0] = er;             di[j0] = ei;
      dr[j0 + s] = fr * wr - fi * wi;
      di[j0 + s] = fr * wi + fi * wr;
    }
    ldsf_t* tp = sr; sr = dr; dr = tp;
    tp = si; si = di; di = tp;
    s <<= 1;
    __syncthreads();
  }
}

__device__ __forceinline__ void reflect_inplace(ldsf_t* zr, ldsf_t* zi,
                                                const float* __restrict__ vre_g,
                                                const float* __restrict__ vim_g,
                                                float fac, ldsf_t* red, int tid) {
  float vr[8], vi[8], zre[8], zim[8];
  float ar = 0.f, ai = 0.f;
#pragma unroll
  for (int jj = 0; jj < 8; ++jj) {
    int j = tid + jj * 256;
    vr[jj] = vre_g[j]; vi[jj] = vim_g[j];
    zre[jj] = zr[j];   zim[jj] = zi[j];
    ar += zre[jj] * vr[jj] + zim[jj] * vi[jj];   // Re(z * conj(v))
    ai += zim[jj] * vr[jj] - zre[jj] * vi[jj];   // Im(z * conj(v))
  }
#pragma unroll
  for (int off = 32; off; off >>= 1) {
    ar += __shfl_down(ar, off);
    ai += __shfl_down(ai, off);
  }
  if ((tid & 63) == 0) { red[(tid >> 6) * 2] = ar; red[(tid >> 6) * 2 + 1] = ai; }
  __syncthreads();
  float vzr = red[0] + red[2] + red[4] + red[6];
  float vzi = red[1] + red[3] + red[5] + red[7];
  __syncthreads();   // red safe for reuse
  float cr = fac * vzr, ci = fac * vzi;
#pragma unroll
  for (int jj = 0; jj < 8; ++jj) {
    int j = tid + jj * 256;
    zr[j] = zre[jj] - (cr * vr[jj] - ci * vi[jj]);
    zi[j] = zim[jj] - (cr * vi[jj] + ci * vr[jj]);
  }
}

__global__ __launch_bounds__(256) void urnn_z(
    const float* __restrict__ state, const float* __restrict__ imul,
    const float* __restrict__ T,
    const float* __restrict__ r1re, const float* __restrict__ r1im,
    const float* __restrict__ r2re, const float* __restrict__ r2im,
    const float* __restrict__ bh, const int* __restrict__ perm,
    float* __restrict__ out) {
  __shared__ float Xre[2048], Xim[2048], Yre[2048], Yim[2048];
  __shared__ float Wc_s[1024], Ws_s[1024];
  __shared__ float red_s[8];

  const int r = blockIdx.x, tid = threadIdx.x;
  const float fac1 = T[12288], fac2 = T[12289];

  ldsf_t* Xr = (ldsf_t*)Xre; ldsf_t* Xi = (ldsf_t*)Xim;
  ldsf_t* Yr = (ldsf_t*)Yre; ldsf_t* Yi = (ldsf_t*)Yim;
  ldsf_t* Wc = (ldsf_t*)Wc_s; ldsf_t* Ws = (ldsf_t*)Ws_s;
  ldsf_t* red = (ldsf_t*)red_s;

  // twiddles: Wt[k] = exp(-2*pi*i * k/2048), k<1024
  for (int k = tid; k < 1024; k += 256) {
    float s, c;
    sincosf(-6.28318530717958647692f * ((float)k * (1.0f / 2048.0f)), &s, &c);
    Wc[k] = c; Ws[k] = s;
  }

  // load state row + d1 rotation
  const float* srow = state + (size_t)r * NDIM;
#pragma unroll
  for (int jj = 0; jj < 8; ++jj) {
    int j = tid + jj * 256;
    float re = srow[j], im = srow[j + NHALF];
    float c = T[j], s = T[2048 + j];
    Xr[j] = re * c - im * s;
    Xi[j] = re * s + im * c;
  }
  __syncthreads();

  ldsf_t *sr = Xr, *si = Xi, *dr = Yr, *di = Yi;

  fft_stages(sr, si, dr, di, Wc, Ws, tid, 1.0f);            // forward FFT
  reflect_inplace(sr, si, r1re, r1im, fac1, red, tid);      // Householder 1
  __syncthreads();                                           // gather needs all writes visible

  // permutation gather + d2 rotation (ifft 1/N folded into T2)
#pragma unroll
  for (int jj = 0; jj < 8; ++jj) {
    int j = tid + jj * 256;
    int idx = perm[j];
    float zr = sr[idx], zi = si[idx];
    float c = T[4096 + j], s = T[6144 + j];
    dr[j] = zr * c - zi * s;
    di[j] = zr * s + zi * c;
  }
  __syncthreads();
  { ldsf_t* tp = sr; sr = dr; dr = tp; tp = si; si = di; di = tp; }

  fft_stages(sr, si, dr, di, Wc, Ws, tid, -1.0f);           // inverse FFT (conj twiddles)
  reflect_inplace(sr, si, r2re, r2im, fac2, red, tid);      // Householder 2

  // d3 rotation + add inputs_c + modReLU + write
  const float* irow = imul + (size_t)r * NDIM;
  float* orow = out + (size_t)r * NDIM;
#pragma unroll
  for (int jj = 0; jj < 8; ++jj) {
    int j = tid + jj * 256;
    float c3 = T[8192 + j], s3 = T[10240 + j];
    float zre = sr[j], zim = si[j];
    float pr = irow[j] + (zre * c3 - zim * s3);
    float pi = irow[j + NHALF] + (zre * s3 + zim * c3);
    float norm = sqrtf(pr * pr + pi * pi);
    float scale = fmaxf(norm + bh[j], 0.0f) / (norm + 1e-6f);
    orow[j] = pr * scale;
    orow[j + NHALF] = pi * scale;
  }
}

// ---------------- launch ----------------
extern "C" void kernel_launch(void* const* d_in, const int* in_sizes, int n_in,
                              void* d_out, int out_size, void* d_ws, size_t ws_size,
                              hipStream_t stream) {
  const float* inputs = (const float*)d_in[0];
  const float* state  = (const float*)d_in[1];
  const float* w_ih   = (const float*)d_in[2];
  const float* b_h    = (const float*)d_in[3];
  const float* d1_w   = (const float*)d_in[4];
  const float* r1_re  = (const float*)d_in[5];
  const float* r1_im  = (const float*)d_in[6];
  const float* d2_w   = (const float*)d_in[7];
  const float* r2_re  = (const float*)d_in[8];
  const float* r2_im  = (const float*)d_in[9];
  const float* d3_w   = (const float*)d_in[10];
  const int*   perm   = (const int*)d_in[11];
  float* out = (float*)d_out;
  (void)in_sizes; (void)n_in; (void)out_size; (void)ws_size;

  // ws layout: imul 128MB | Acvt 32MB | Wcvt 16MB | T ~48KB  (total ~184.6MB)
  char* ws = (char*)d_ws;
  float*          imul = (float*)(ws);
  unsigned short* Acvt = (unsigned short*)(ws + 134217728ull);
  unsigned short* Wcvt = (unsigned short*)(ws + 134217728ull + 33554432ull);
  float*          T    = (float*)(ws + 134217728ull + 33554432ull + 16777216ull);

  cvt_split<<<4096, 256, 0, stream>>>(inputs, Acvt, BATCH);
  cvt_split<<<2048, 256, 0, stream>>>(w_ih, Wcvt, NDIM);
  tables_kernel<<<1, 256, 0, stream>>>(d1_w, r1_re, r1_im, d2_w, r2_re, r2_im, d3_w, T);
  gemm_split<<<2048, 256, 0, stream>>>(Acvt, Wcvt, imul);
  urnn_z<<<BATCH, 256, 0, stream>>>(state, imul, T, r1_re, r1_im, r2_re, r2_im, b_h, perm, out);
}

// Round 2
// 586.022 us; speedup vs baseline: 1.0975x; 1.0975x over previous
//
#include <hip/hip_runtime.h>
#include <hip/hip_bf16.h>

#define GLOBAL_AS __attribute__((address_space(1)))
#define LDS_AS    __attribute__((address_space(3)))

typedef __bf16 bf16x8 __attribute__((ext_vector_type(8)));
typedef float  f32x4  __attribute__((ext_vector_type(4)));
typedef unsigned short u16x8 __attribute__((ext_vector_type(8)));

#define BATCH  8192
#define KDIM   1024
#define NDIM   4096
#define NHALF  2048
#define KTILES 32   // KDIM / 32

// ---------------- fp32 -> bf16 hi/lo split helpers ----------------
__device__ __forceinline__ unsigned short bf16_rne(float f) {
  unsigned int u = __float_as_uint(f);
  u += 0x7fffu + ((u >> 16) & 1u);
  return (unsigned short)(u >> 16);
}
__device__ __forceinline__ float bf16_f32(unsigned short h) {
  return __uint_as_float(((unsigned int)h) << 16);
}

__global__ __launch_bounds__(256) void cvt_split(const float* __restrict__ src,
                                                 unsigned short* __restrict__ dst,
                                                 int rows) {
  int i = blockIdx.x * 256 + threadIdx.x;   // chunk id: 8 k's per chunk
  if (i >= rows * 128) return;
  int m = i >> 7, c = i & 127;
  const float4* s4 = (const float4*)(src + ((size_t)m * KDIM + c * 8));
  float4 x0 = s4[0], x1 = s4[1];
  float xs[8] = {x0.x, x0.y, x0.z, x0.w, x1.x, x1.y, x1.z, x1.w};
  u16x8 hv, lv;
#pragma unroll
  for (int j = 0; j < 8; ++j) {
    unsigned short h = bf16_rne(xs[j]);
    hv[j] = h;
    lv[j] = bf16_rne(xs[j] - bf16_f32(h));
  }
  size_t base = ((size_t)m * KTILES + (c >> 2)) * 64 + (size_t)(c & 3) * 8;
  *(u16x8*)(dst + base) = hv;        // hi chunk
  *(u16x8*)(dst + base + 32) = lv;   // lo chunk
}

// ---------------- tables: rotation cos/sin + Householder factors ----------------
// T layout (floats): [0)=T1c[2048] [2048)=T1s [4096)=T2c*(1/2048) [6144)=T2s*(1/2048)
//                    [8192)=T3c [10240)=T3s [12288]=fac1 [12289]=fac2
__global__ __launch_bounds__(256) void tables_kernel(
    const float* __restrict__ d1, const float* __restrict__ r1re, const float* __restrict__ r1im,
    const float* __restrict__ d2, const float* __restrict__ r2re, const float* __restrict__ r2im,
    const float* __restrict__ d3, float* __restrict__ T) {
  __shared__ float red[8];
  int tid = threadIdx.x;
  const float invN = 1.0f / 2048.0f;   // fold ifft 1/N into d2 rotation (linear ops commute)
  for (int j = tid; j < NHALF; j += 256) {
    float s, c;
    sincosf(d1[j], &s, &c); T[j] = c;            T[2048 + j] = s;
    sincosf(d2[j], &s, &c); T[4096 + j] = c * invN; T[6144 + j] = s * invN;
    sincosf(d3[j], &s, &c); T[8192 + j] = c;     T[10240 + j] = s;
  }
  float n1 = 0.f, n2 = 0.f;
  for (int j = tid; j < NHALF; j += 256) {
    n1 += r1re[j] * r1re[j] + r1im[j] * r1im[j];
    n2 += r2re[j] * r2re[j] + r2im[j] * r2im[j];
  }
#pragma unroll
  for (int off = 32; off; off >>= 1) {
    n1 += __shfl_down(n1, off);
    n2 += __shfl_down(n2, off);
  }
  if ((tid & 63) == 0) { red[(tid >> 6) * 2] = n1; red[(tid >> 6) * 2 + 1] = n2; }
  __syncthreads();
  if (tid == 0) {
    T[12288] = 2.0f / (red[0] + red[2] + red[4] + red[6]);
    T[12289] = 2.0f / (red[1] + red[3] + red[5] + red[7]);
  }
}

// ---------------- split-bf16 x3 MFMA GEMM (unchanged from R1) ----------------
__global__ __launch_bounds__(256) void gemm_split(const unsigned short* __restrict__ Acvt,
                                                  const unsigned short* __restrict__ Wcvt,
                                                  float* __restrict__ C) {
  __shared__ __attribute__((aligned(16))) unsigned short sA[128 * 64];
  __shared__ __attribute__((aligned(16))) unsigned short sW[128 * 64];

  int bid = blockIdx.x;
  int swz = (bid & 7) * 256 + (bid >> 3);   // 2048 blocks, bijective XCD swizzle
  int bm = swz >> 5;                         // 64 M-tiles
  int bn = swz & 31;                         // 32 N-tiles

  int tid = threadIdx.x;
  int w = tid >> 6, l = tid & 63;
  int wr = w >> 1, wc = w & 1;               // wave 2x2 grid
  int g = l >> 4;                            // k-chunk group (8 bf16 each)

  f32x4 acc[4][4] = {};

#pragma unroll 1
  for (int kt = 0; kt < KTILES; ++kt) {
    __syncthreads();
#pragma unroll
    for (int i = 0; i < 4; ++i) {
      int rgrp = (w * 4 + i) * 8;
      int row = rgrp + (l >> 3);
      int chunk = (l & 7) ^ (l >> 3);
      const unsigned short* srcA = Acvt + (((size_t)(bm * 128 + row)) * KTILES + kt) * 64 + chunk * 8;
      const unsigned short* srcW = Wcvt + (((size_t)(bn * 128 + row)) * KTILES + kt) * 64 + chunk * 8;
      __builtin_amdgcn_global_load_lds((GLOBAL_AS const void*)srcA, (LDS_AS void*)(sA + rgrp * 64), 16, 0, 0);
      __builtin_amdgcn_global_load_lds((GLOBAL_AS const void*)srcW, (LDS_AS void*)(sW + rgrp * 64), 16, 0, 0);
    }
    __syncthreads();

    bf16x8 a_hi[4], a_lo[4], b_hi[4], b_lo[4];
#pragma unroll
    for (int mi = 0; mi < 4; ++mi) {
      int row = wr * 64 + mi * 16 + (l & 15);
      int ph = g ^ (row & 7);
      a_hi[mi] = *(const bf16x8*)&sA[row * 64 + ph * 8];
      a_lo[mi] = *(const bf16x8*)&sA[row * 64 + (ph ^ 4) * 8];
    }
#pragma unroll
    for (int ni = 0; ni < 4; ++ni) {
      int row = wc * 64 + ni * 16 + (l & 15);
      int ph = g ^ (row & 7);
      b_hi[ni] = *(const bf16x8*)&sW[row * 64 + ph * 8];
      b_lo[ni] = *(const bf16x8*)&sW[row * 64 + (ph ^ 4) * 8];
    }
#pragma unroll
    for (int mi = 0; mi < 4; ++mi)
#pragma unroll
      for (int ni = 0; ni < 4; ++ni) {
        acc[mi][ni] = __builtin_amdgcn_mfma_f32_16x16x32_bf16(a_hi[mi], b_hi[ni], acc[mi][ni], 0, 0, 0);
        acc[mi][ni] = __builtin_amdgcn_mfma_f32_16x16x32_bf16(a_hi[mi], b_lo[ni], acc[mi][ni], 0, 0, 0);
        acc[mi][ni] = __builtin_amdgcn_mfma_f32_16x16x32_bf16(a_lo[mi], b_hi[ni], acc[mi][ni], 0, 0, 0);
      }
  }

  int r0 = bm * 128 + wr * 64 + g * 4;
  int c0 = bn * 128 + wc * 64 + (l & 15);
#pragma unroll
  for (int mi = 0; mi < 4; ++mi)
#pragma unroll
    for (int ni = 0; ni < 4; ++ni)
#pragma unroll
      for (int i = 0; i < 4; ++i)
        C[(size_t)(r0 + mi * 16 + i) * NDIM + (c0 + ni * 16)] = acc[mi][ni][i];
}

// ---------------- fused complex pipeline: register FFT (radix 8*8*8*4) ----------------
// LDS float2 index swizzle: optimal 4-words/bank for every stage pattern (see R2 notes)
__device__ __forceinline__ int SW(int i) { return i ^ ((i >> 4) & 15); }

__device__ __forceinline__ float2 cmul(float2 a, float2 b) {
  return make_float2(a.x * b.x - a.y * b.y, a.x * b.y + a.y * b.x);
}

// 8-point DFT, SGN=-1 forward (w = e^{-2pi i/8}), SGN=+1 inverse
template<int SGN>
__device__ __forceinline__ void dft8(const float2 a[8], float2 X[8]) {
  const float Sf = (float)SGN;
  // evens a0 a2 a4 a6
  float t0r = a[0].x + a[4].x, t0i = a[0].y + a[4].y;
  float t2r = a[0].x - a[4].x, t2i = a[0].y - a[4].y;
  float t1r = a[2].x + a[6].x, t1i = a[2].y + a[6].y;
  float t3r = a[2].x - a[6].x, t3i = a[2].y - a[6].y;
  float E0r = t0r + t1r, E0i = t0i + t1i, E2r = t0r - t1r, E2i = t0i - t1i;
  float E1r = t2r - Sf * t3i, E1i = t2i + Sf * t3r;
  float E3r = t2r + Sf * t3i, E3i = t2i - Sf * t3r;
  // odds a1 a3 a5 a7
  float s0r = a[1].x + a[5].x, s0i = a[1].y + a[5].y;
  float s2r = a[1].x - a[5].x, s2i = a[1].y - a[5].y;
  float s1r = a[3].x + a[7].x, s1i = a[3].y + a[7].y;
  float s3r = a[3].x - a[7].x, s3i = a[3].y - a[7].y;
  float O0r = s0r + s1r, O0i = s0i + s1i, O2r = s0r - s1r, O2i = s0i - s1i;
  float O1r = s2r - Sf * s3i, O1i = s2i + Sf * s3r;
  float O3r = s2r + Sf * s3i, O3i = s2i - Sf * s3r;
  const float C2 = 0.70710678118654752440f;
  float u0r = O0r, u0i = O0i;
  float u1r = C2 * (O1r - Sf * O1i), u1i = C2 * (O1i + Sf * O1r);
  float u2r = -Sf * O2i, u2i = Sf * O2r;
  float u3r = -C2 * (O3r + Sf * O3i), u3i = C2 * (Sf * O3r - O3i);
  X[0] = make_float2(E0r + u0r, E0i + u0i); X[4] = make_float2(E0r - u0r, E0i - u0i);
  X[1] = make_float2(E1r + u1r, E1i + u1i); X[5] = make_float2(E1r - u1r, E1i - u1i);
  X[2] = make_float2(E2r + u2r, E2i + u2i); X[6] = make_float2(E2r - u2r, E2i - u2i);
  X[3] = make_float2(E3r + u3r, E3i + u3i); X[7] = make_float2(E3r - u3r, E3i - u3i);
}

// Stockham radix-8 stage: out[8*ps + q + m*s] = W_N^{ps*m} * DFT8_m(src[t + 256*j])
template<int SGN, int S>
__device__ __forceinline__ void radix8_wr(const float2 a[8], float2* dst, const float2* Tw, int t) {
  float2 X[8];
  dft8<SGN>(a, X);
  int q = t & (S - 1);
  int ps = t - q;
  float2 tw = Tw[ps];
  float2 w1 = make_float2(tw.x, (SGN < 0) ? tw.y : -tw.y);
  float2 w2 = cmul(w1, w1), w3 = cmul(w2, w1), w4 = cmul(w2, w2);
  float2 w5 = cmul(w4, w1), w6 = cmul(w4, w2), w7 = cmul(w4, w3);
  int base = 8 * ps + q;
  dst[SW(base)]         = X[0];
  dst[SW(base + S)]     = cmul(X[1], w1);
  dst[SW(base + 2 * S)] = cmul(X[2], w2);
  dst[SW(base + 3 * S)] = cmul(X[3], w3);
  dst[SW(base + 4 * S)] = cmul(X[4], w4);
  dst[SW(base + 5 * S)] = cmul(X[5], w5);
  dst[SW(base + 6 * S)] = cmul(X[6], w6);
  dst[SW(base + 7 * S)] = cmul(X[7], w7);
}

template<int SGN, int S>
__device__ __forceinline__ void radix8_ld(const float2* src, float2* dst, const float2* Tw, int t) {
  float2 a[8];
#pragma unroll
  for (int j = 0; j < 8; ++j) a[j] = src[SW(t + 256 * j)];
  radix8_wr<SGN, S>(a, dst, Tw, t);
}

// final radix-4 stage (s=512, p=0, no twiddle): z[2m+h] holds position t + 256*(2m+h)
template<int SGN>
__device__ __forceinline__ void radix4_final(const float2* src, float2 z[8], int t) {
  const float Sf = (float)SGN;
#pragma unroll
  for (int h = 0; h < 2; ++h) {
    int q = t + 256 * h;
    float2 a0 = src[SW(q)], a1 = src[SW(q + 512)], a2 = src[SW(q + 1024)], a3 = src[SW(q + 1536)];
    float t0r = a0.x + a2.x, t0i = a0.y + a2.y, t2r = a0.x - a2.x, t2i = a0.y - a2.y;
    float t1r = a1.x + a3.x, t1i = a1.y + a3.y, t3r = a1.x - a3.x, t3i = a1.y - a3.y;
    z[0 + h] = make_float2(t0r + t1r, t0i + t1i);
    z[4 + h] = make_float2(t0r - t1r, t0i - t1i);
    z[2 + h] = make_float2(t2r - Sf * t3i, t2i + Sf * t3r);
    z[6 + h] = make_float2(t2r + Sf * t3i, t2i - Sf * t3r);
  }
}

// Householder reflect on register-held row (z[j] at position t+256j)
__device__ __forceinline__ void reflect_reg(float2 z[8],
                                            const float* __restrict__ vre,
                                            const float* __restrict__ vim,
                                            float fac, volatile float* red, int t) {
  float vr[8], vi[8];
  float ar = 0.f, ai = 0.f;
#pragma unroll
  for (int j = 0; j < 8; ++j) {
    int o = t + 256 * j;
    vr[j] = vre[o]; vi[j] = vim[o];
    ar += z[j].x * vr[j] + z[j].y * vi[j];   // Re(z * conj(v))
    ai += z[j].y * vr[j] - z[j].x * vi[j];   // Im(z * conj(v))
  }
#pragma unroll
  for (int off = 32; off; off >>= 1) {
    ar += __shfl_down(ar, off);
    ai += __shfl_down(ai, off);
  }
  int w = t >> 6;
  if ((t & 63) == 0) { red[w * 2] = ar; red[w * 2 + 1] = ai; }
  __syncthreads();
  float vzr = red[0] + red[2] + red[4] + red[6];
  float vzi = red[1] + red[3] + red[5] + red[7];
  __syncthreads();
  float cr = fac * vzr, ci = fac * vzi;
#pragma unroll
  for (int j = 0; j < 8; ++j) {
    z[j].x -= cr * vr[j] - ci * vi[j];
    z[j].y -= cr * vi[j] + ci * vr[j];
  }
}

__global__ __launch_bounds__(256, 4) void urnn_z(
    const float* __restrict__ state, const float* __restrict__ imul,
    const float* __restrict__ T,
    const float* __restrict__ r1re, const float* __restrict__ r1im,
    const float* __restrict__ r2re, const float* __restrict__ r2im,
    const float* __restrict__ bh, const int* __restrict__ perm,
    float* __restrict__ out) {
  __shared__ __attribute__((aligned(16))) float2 Abuf[2048];
  __shared__ __attribute__((aligned(16))) float2 Bbuf[2048];
  __shared__ __attribute__((aligned(16))) float2 Tw[256];
  __shared__ float red[8];

  const int t = threadIdx.x, r = blockIdx.x;
  const float fac1 = T[12288], fac2 = T[12289];

  // twiddle table: Tw[k] = e^{-2pi i k/2048}, k<256 (one entry per thread)
  {
    float sn, cs;
    sincosf(-6.28318530717958647692f * ((float)t * (1.0f / 2048.0f)), &sn, &cs);
    Tw[t] = make_float2(cs, sn);
  }

  // load state row + d1 rotation straight into registers (positions t+256j)
  const float* srow = state + (size_t)r * NDIM;
  float2 a[8];
#pragma unroll
  for (int j = 0; j < 8; ++j) {
    int o = t + 256 * j;
    float re = srow[o], im = srow[o + NHALF];
    float c = T[o], s = T[2048 + o];
    a[j] = make_float2(re * c - im * s, re * s + im * c);
  }
  radix8_wr<-1, 1>(a, Abuf, Tw, t);           // fwd stage 1 (regs -> A)
  __syncthreads();
  radix8_ld<-1, 8>(Abuf, Bbuf, Tw, t);        // fwd stage 2
  __syncthreads();
  radix8_ld<-1, 64>(Bbuf, Abuf, Tw, t);       // fwd stage 3
  __syncthreads();
  float2 z[8];
  radix4_final<-1>(Abuf, z, t);               // fwd stage 4 -> regs

  reflect_reg(z, r1re, r1im, fac1, red, t);   // Householder 1 (in regs)

  // stash for permutation gather
#pragma unroll
  for (int j = 0; j < 8; ++j) Bbuf[SW(t + 256 * j)] = z[j];
  __syncthreads();

  // perm gather + d2 rotation (ifft 1/N folded into T2) -> regs for inv stage 1
#pragma unroll
  for (int j = 0; j < 8; ++j) {
    int o = t + 256 * j;
    int pp = perm[o];
    float2 zz = Bbuf[SW(pp)];
    float c = T[4096 + o], s = T[6144 + o];
    a[j] = make_float2(zz.x * c - zz.y * s, zz.x * s + zz.y * c);
  }
  radix8_wr<+1, 1>(a, Abuf, Tw, t);           // inv stage 1 (regs -> A)
  __syncthreads();
  radix8_ld<+1, 8>(Abuf, Bbuf, Tw, t);        // inv stage 2
  __syncthreads();
  radix8_ld<+1, 64>(Bbuf, Abuf, Tw, t);       // inv stage 3
  __syncthreads();
  radix4_final<+1>(Abuf, z, t);               // inv stage 4 -> regs

  reflect_reg(z, r2re, r2im, fac2, red, t);   // Householder 2 (in regs)

  // d3 rotation + add inputs_c + modReLU + store
  const float* irow = imul + (size_t)r * NDIM;
  float* orow = out + (size_t)r * NDIM;
#pragma unroll
  for (int j = 0; j < 8; ++j) {
    int o = t + 256 * j;
    float c3 = T[8192 + o], s3 = T[10240 + o];
    float pr = irow[o] + (z[j].x * c3 - z[j].y * s3);
    float pi = irow[o + NHALF] + (z[j].x * s3 + z[j].y * c3);
    float norm = sqrtf(pr * pr + pi * pi);
    float scale = fmaxf(norm + bh[o], 0.0f) / (norm + 1e-6f);
    orow[o] = pr * scale;
    orow[o + NHALF] = pi * scale;
  }
}

// ---------------- launch ----------------
extern "C" void kernel_launch(void* const* d_in, const int* in_sizes, int n_in,
                              void* d_out, int out_size, void* d_ws, size_t ws_size,
                              hipStream_t stream) {
  const float* inputs = (const float*)d_in[0];
  const float* state  = (const float*)d_in[1];
  const float* w_ih   = (const float*)d_in[2];
  const float* b_h    = (const float*)d_in[3];
  const float* d1_w   = (const float*)d_in[4];
  const float* r1_re  = (const float*)d_in[5];
  const float* r1_im  = (const float*)d_in[6];
  const float* d2_w   = (const float*)d_in[7];
  const float* r2_re  = (const float*)d_in[8];
  const float* r2_im  = (const float*)d_in[9];
  const float* d3_w   = (const float*)d_in[10];
  const int*   perm   = (const int*)d_in[11];
  float* out = (float*)d_out;
  (void)in_sizes; (void)n_in; (void)out_size; (void)ws_size;

  // ws layout: imul 128MB | Acvt 32MB | Wcvt 16MB | T ~48KB
  char* ws = (char*)d_ws;
  float*          imul = (float*)(ws);
  unsigned short* Acvt = (unsigned short*)(ws + 134217728ull);
  unsigned short* Wcvt = (unsigned short*)(ws + 134217728ull + 33554432ull);
  float*          T    = (float*)(ws + 134217728ull + 33554432ull + 16777216ull);

  cvt_split<<<4096, 256, 0, stream>>>(inputs, Acvt, BATCH);
  cvt_split<<<2048, 256, 0, stream>>>(w_ih, Wcvt, NDIM);
  tables_kernel<<<1, 256, 0, stream>>>(d1_w, r1_re, r1_im, d2_w, r2_re, r2_im, d3_w, T);
  gemm_split<<<2048, 256, 0, stream>>>(Acvt, Wcvt, imul);
  urnn_z<<<BATCH, 256, 0, stream>>>(state, imul, T, r1_re, r1_im, r2_re, r2_im, b_h, perm, out);
}